// Round 1
// baseline (364.315 us; speedup 1.0000x reference)
//
#include <hip/hip_runtime.h>
#include <math.h>

#define KC 24
constexpr int D = 16;
constexpr int B = 4;
constexpr int N = 512 * 1024;          // points per image, 2^19
constexpr float DELTA_VAR = 1.0f;
constexpr float DELTA_DIST = 2.0f;

constexpr int REP = 8;                 // LDS accumulator replicas (replica = lane&7)
constexpr int RS  = KC * 17;           // 408 words per sum replica
constexpr int CS  = 33;
constexpr int PTS = 1024;              // points per block
constexpr int BLOCKS = (B * N) / PTS;  // 2048 -> 8 blocks/CU nominal
constexpr int SL = 8;                  // global accumulator slices (cuts atomic chains 8x)

// ws (floats): g_sums [SL][B*KC*D]=12288 | g_cnt [SL][B*KC]=768 | g_varp [64]

// ---------------- Pass 1: per-cluster sums + counts (16-deep batched loads) ----------------
__global__ __launch_bounds__(256) void k_sums(const float* __restrict__ data,
                                              const int* __restrict__ labels,
                                              float* __restrict__ g_sums,
                                              float* __restrict__ g_cnt) {
    __shared__ float s_sum[REP * RS];      // 13 KB
    __shared__ float s_cnt[REP * CS];
    const int t = threadIdx.x;
    for (int i = t; i < REP * RS; i += 256) s_sum[i] = 0.f;
    for (int i = t; i < REP * CS; i += 256) s_cnt[i] = 0.f;
    __syncthreads();

    const int chunk = blockIdx.x * PTS;
    const int b     = chunk >> 19;
    const int n0    = (chunk & (N - 1)) + t * 4;

    const int4 lab = *(const int4*)(labels + chunk + t * 4);  // labels of THIS thread's 4 points
    const int rbase = (t & 7) * RS;
    const int ax = rbase + lab.x * 17;
    const int ay = rbase + lab.y * 17;
    const int az = rbase + lab.z * 17;
    const int aw = rbase + lab.w * 17;

    // issue ALL 16 plane loads back-to-back: 16 KB in flight per wave
    const float* base = data + (size_t)(b * D) * N + n0;
    float4 v[D];
#pragma unroll
    for (int d = 0; d < D; ++d) v[d] = *(const float4*)(base + (size_t)d * N);

    // counts don't depend on data -> do them under the load latency
    const int cbase = (t & 7) * CS;
    atomicAdd(&s_cnt[cbase + lab.x], 1.f);
    atomicAdd(&s_cnt[cbase + lab.y], 1.f);
    atomicAdd(&s_cnt[cbase + lab.z], 1.f);
    atomicAdd(&s_cnt[cbase + lab.w], 1.f);

#pragma unroll
    for (int d = 0; d < D; ++d) {          // compiler stages vmcnt(15-d) waits
        atomicAdd(&s_sum[ax + d], v[d].x);
        atomicAdd(&s_sum[ay + d], v[d].y);
        atomicAdd(&s_sum[az + d], v[d].z);
        atomicAdd(&s_sum[aw + d], v[d].w);
    }
    __syncthreads();

    // epilogue: rotated order + per-slice targets so same-address chains are 64 deep, not 512
    const int slice = blockIdx.x & (SL - 1);
    float* gs = g_sums + slice * (B * KC * D) + b * (KC * D);
    float* gc = g_cnt  + slice * (B * KC)     + b * KC;
    const int rot = (blockIdx.x * 131) & 255;
    for (int i = t; i < KC * D; i += 256) {
        int j = (i + rot) % (KC * D);
        int c = j >> 4, d = j & 15;
        float s = 0.f;
#pragma unroll
        for (int r = 0; r < REP; ++r) s += s_sum[r * RS + c * 17 + d];
        atomicAdd(&gs[j], s);
    }
    if (t < KC) {
        float s = 0.f;
#pragma unroll
        for (int r = 0; r < REP; ++r) s += s_cnt[r * CS + t];
        atomicAdd(&gc[t], s);
    }
}

// ---------------- Pass 2: hinged variance — NO LDS atomics, 16-deep batched loads ----------------
__global__ __launch_bounds__(256) void k_var(const float* __restrict__ data,
                                             const int* __restrict__ labels,
                                             const float* __restrict__ g_sums,
                                             const float* __restrict__ g_cnt,
                                             float* __restrict__ g_varp) {
    __shared__ float s_c[KC * 17];
    __shared__ float s_ic[KC];
    __shared__ float s_part[4];
    const int t = threadIdx.x;
    const int chunk = blockIdx.x * PTS;
    const int b     = chunk >> 19;
    const int n0    = (chunk & (N - 1)) + t * 4;

    if (t < KC) {
        float cn = 0.f;
#pragma unroll
        for (int r = 0; r < SL; ++r) cn += g_cnt[r * (B * KC) + b * KC + t];
        s_ic[t] = 1.f / cn;
    }
    __syncthreads();
    for (int i = t; i < KC * D; i += 256) {
        int c = i >> 4, d = i & 15;
        float s = 0.f;
#pragma unroll
        for (int r = 0; r < SL; ++r) s += g_sums[r * (B * KC * D) + b * (KC * D) + i];
        s_c[c * 17 + d] = s * s_ic[c];
    }
    __syncthreads();

    const int4 lab = *(const int4*)(labels + chunk + t * 4);
    const int ax = lab.x * 17, ay = lab.y * 17, az = lab.z * 17, aw = lab.w * 17;

    const float* base = data + (size_t)(b * D) * N + n0;
    float4 v[D];
#pragma unroll
    for (int d = 0; d < D; ++d) v[d] = *(const float4*)(base + (size_t)d * N);

    float4 acc = {0.f, 0.f, 0.f, 0.f};
#pragma unroll
    for (int d = 0; d < D; ++d) {
        float df;
        df = v[d].x - s_c[ax + d]; acc.x += df * df;
        df = v[d].y - s_c[ay + d]; acc.y += df * df;
        df = v[d].z - s_c[az + d]; acc.z += df * df;
        df = v[d].w - s_c[aw + d]; acc.w += df * df;
    }
    float h, hsum;
    h = fmaxf(sqrtf(acc.x) - DELTA_VAR, 0.f); hsum  = h * h * s_ic[lab.x];
    h = fmaxf(sqrtf(acc.y) - DELTA_VAR, 0.f); hsum += h * h * s_ic[lab.y];
    h = fmaxf(sqrtf(acc.z) - DELTA_VAR, 0.f); hsum += h * h * s_ic[lab.z];
    h = fmaxf(sqrtf(acc.w) - DELTA_VAR, 0.f); hsum += h * h * s_ic[lab.w];

    for (int o = 32; o > 0; o >>= 1) hsum += __shfl_down(hsum, o, 64);
    if ((t & 63) == 0) s_part[t >> 6] = hsum;
    __syncthreads();
    if (t == 0)
        atomicAdd(&g_varp[blockIdx.x & 63],
                  s_part[0] + s_part[1] + s_part[2] + s_part[3]);
}

// ---------------- Finalize: var + dist + reg -> scalar ----------------
__global__ __launch_bounds__(128) void k_final(const float* __restrict__ g_sums,
                                               const float* __restrict__ g_cnt,
                                               const float* __restrict__ g_varp,
                                               float* __restrict__ out) {
    __shared__ float s_c[B * KC * 17];
    __shared__ float s_red[2];
    const int t = threadIdx.x;

    float acc = 0.f;
    if (t < B * KC) {               // reg term + center build (sum the SL slices)
        float cnt = 0.f;
#pragma unroll
        for (int r = 0; r < SL; ++r) cnt += g_cnt[r * (B * KC) + t];
        float ns = 0.f;
        for (int d = 0; d < D; ++d) {
            float s = 0.f;
#pragma unroll
            for (int r = 0; r < SL; ++r) s += g_sums[r * (B * KC * D) + t * D + d];
            float c = s / cnt;
            s_c[t * 17 + d] = c;
            ns += c * c;
        }
        acc = sqrtf(ns) / (float)KC;
    }
    if (t < 64) acc += g_varp[t];   // var term partials
    __syncthreads();

    float dacc = 0.f;  // raw sum over [B,K,K] incl. diagonal (= delta_dist^2 each)
    for (int idx = t; idx < B * KC * KC; idx += 128) {
        int b = idx / (KC * KC);
        int r = idx % (KC * KC);
        int i = r / KC, j = r % KC;
        float hd;
        if (i == j) {
            hd = DELTA_DIST * DELTA_DIST;
        } else {
            const float* ci = &s_c[(b * KC + i) * 17];
            const float* cj = &s_c[(b * KC + j) * 17];
            float sq = 0.f;
            for (int d = 0; d < D; ++d) { float df = ci[d] - cj[d]; sq += df * df; }
            float hh = fmaxf(DELTA_DIST - sqrtf(sq), 0.f);
            hd = hh * hh;
        }
        dacc += hd;
    }
    float total = acc + dacc / (2.f * KC * (KC - 1));

    for (int o = 32; o > 0; o >>= 1) total += __shfl_down(total, o, 64);
    if ((t & 63) == 0) s_red[t >> 6] = total;
    __syncthreads();
    if (t == 0) out[0] = (s_red[0] + s_red[1]) / (float)B;
}

extern "C" void kernel_launch(void* const* d_in, const int* in_sizes, int n_in,
                              void* d_out, int out_size, void* d_ws, size_t ws_size,
                              hipStream_t stream) {
    const float* data  = (const float*)d_in[0];
    const int* labels  = (const int*)d_in[1];
    float* ws = (float*)d_ws;
    float* g_sums = ws;                                 // SL * 1536 = 12288
    float* g_cnt  = g_sums + SL * (B * KC * D);         // SL * 96   = 768
    float* g_varp = g_cnt  + SL * (B * KC);             // 64

    hipMemsetAsync(d_ws, 0,
                   (SL * (B * KC * D) + SL * (B * KC) + 64) * sizeof(float), stream);

    k_sums<<<BLOCKS, 256, 0, stream>>>(data, labels, g_sums, g_cnt);
    k_var <<<BLOCKS, 256, 0, stream>>>(data, labels, g_sums, g_cnt, g_varp);
    k_final<<<1, 128, 0, stream>>>(g_sums, g_cnt, g_varp, (float*)d_out);
}

// Round 2
// 353.128 us; speedup vs baseline: 1.0317x; 1.0317x over previous
//
#include <hip/hip_runtime.h>
#include <math.h>

#define KC 24
constexpr int D = 16;
constexpr int B = 4;
constexpr int N = 512 * 1024;          // points per image, 2^19
constexpr float DELTA_VAR = 1.0f;
constexpr float DELTA_DIST = 2.0f;

constexpr int REP = 8;                 // LDS accumulator replicas (replica = lane&7)
constexpr int RS  = KC * 17;           // 408 words per sum replica
constexpr int CS  = 33;
constexpr int PTS = 4096;              // points per block (16 KB contiguous per plane-chunk)
constexpr int BLOCKS = (B * N) / PTS;  // 512 -> 2 blocks/CU, 8 waves/CU
constexpr int SL = 8;                  // global accumulator slices

// ws (floats): g_sums [SL][B*KC*D]=12288 | g_cnt [SL][B*KC]=768 | g_varp [64]

// ---------------- Pass 1: per-cluster sums + counts (d-sequential streaming) ----------------
// Each block streams 16 KB contiguous per plane, one plane at a time (1-plane prefetch).
// Per-thread state: 16 labels (4 int4) + LDS addr bases in registers across the d-loop.
__global__ __launch_bounds__(256) void k_sums(const float* __restrict__ data,
                                              const int* __restrict__ labels,
                                              float* __restrict__ g_sums,
                                              float* __restrict__ g_cnt) {
    __shared__ float s_sum[REP * RS];      // 13 KB
    __shared__ float s_cnt[REP * CS];
    const int t = threadIdx.x;

    const int chunk = blockIdx.x * PTS;
    const int b     = chunk >> 19;
    const int n0    = chunk & (N - 1);

    // issue label loads + first plane loads before touching LDS (latency overlap)
    int4 lab[4];
#pragma unroll
    for (int i = 0; i < 4; ++i)
        lab[i] = *(const int4*)(labels + chunk + (i * 256 + t) * 4);

    const float* base = data + (size_t)(b * D) * N + n0;
    float4 v[2][4];
#pragma unroll
    for (int i = 0; i < 4; ++i)
        v[0][i] = *(const float4*)(base + (i * 256 + t) * 4);

    for (int i = t; i < REP * RS; i += 256) s_sum[i] = 0.f;
    for (int i = t; i < REP * CS; i += 256) s_cnt[i] = 0.f;

    const int rbase = (t & 7) * RS;
    int adr[4][4];
#pragma unroll
    for (int i = 0; i < 4; ++i) {
        adr[i][0] = rbase + lab[i].x * 17;
        adr[i][1] = rbase + lab[i].y * 17;
        adr[i][2] = rbase + lab[i].z * 17;
        adr[i][3] = rbase + lab[i].w * 17;
    }
    __syncthreads();

    // counts don't depend on data -> under load latency
    const int cbase = (t & 7) * CS;
#pragma unroll
    for (int i = 0; i < 4; ++i) {
        atomicAdd(&s_cnt[cbase + lab[i].x], 1.f);
        atomicAdd(&s_cnt[cbase + lab[i].y], 1.f);
        atomicAdd(&s_cnt[cbase + lab[i].z], 1.f);
        atomicAdd(&s_cnt[cbase + lab[i].w], 1.f);
    }

#pragma unroll
    for (int d = 0; d < D; ++d) {
        if (d < D - 1) {
#pragma unroll
            for (int i = 0; i < 4; ++i)
                v[(d + 1) & 1][i] =
                    *(const float4*)(base + (size_t)(d + 1) * N + (i * 256 + t) * 4);
        }
#pragma unroll
        for (int i = 0; i < 4; ++i) {
            const float4 c = v[d & 1][i];
            atomicAdd(&s_sum[adr[i][0] + d], c.x);
            atomicAdd(&s_sum[adr[i][1] + d], c.y);
            atomicAdd(&s_sum[adr[i][2] + d], c.z);
            atomicAdd(&s_sum[adr[i][3] + d], c.w);
        }
    }
    __syncthreads();

    // epilogue: rotated order + per-slice targets (chains 16 deep per address)
    const int slice = blockIdx.x & (SL - 1);
    float* gs = g_sums + slice * (B * KC * D) + b * (KC * D);
    float* gc = g_cnt  + slice * (B * KC)     + b * KC;
    const int rot = (blockIdx.x * 131) & 255;
    for (int i = t; i < KC * D; i += 256) {
        int j = (i + rot) % (KC * D);
        int c = j >> 4, d = j & 15;
        float s = 0.f;
#pragma unroll
        for (int r = 0; r < REP; ++r) s += s_sum[r * RS + c * 17 + d];
        atomicAdd(&gs[j], s);
    }
    if (t < KC) {
        float s = 0.f;
#pragma unroll
        for (int r = 0; r < REP; ++r) s += s_cnt[r * CS + t];
        atomicAdd(&gc[t], s);
    }
}

// ---------------- Pass 2: hinged variance (d-sequential, per-point acc in regs) ----------------
__global__ __launch_bounds__(256) void k_var(const float* __restrict__ data,
                                             const int* __restrict__ labels,
                                             const float* __restrict__ g_sums,
                                             const float* __restrict__ g_cnt,
                                             float* __restrict__ g_varp) {
    __shared__ float s_c[KC * 17];
    __shared__ float s_ic[KC];
    __shared__ float s_part[4];
    const int t = threadIdx.x;
    const int chunk = blockIdx.x * PTS;
    const int b     = chunk >> 19;
    const int n0    = chunk & (N - 1);

    // issue per-thread global loads first (latency overlap with center build)
    int4 lab[4];
#pragma unroll
    for (int i = 0; i < 4; ++i)
        lab[i] = *(const int4*)(labels + chunk + (i * 256 + t) * 4);

    const float* base = data + (size_t)(b * D) * N + n0;
    float4 v[2][4];
#pragma unroll
    for (int i = 0; i < 4; ++i)
        v[0][i] = *(const float4*)(base + (i * 256 + t) * 4);

    if (t < KC) {
        float cn = 0.f;
#pragma unroll
        for (int r = 0; r < SL; ++r) cn += g_cnt[r * (B * KC) + b * KC + t];
        s_ic[t] = 1.f / cn;
    }
    __syncthreads();
    for (int i = t; i < KC * D; i += 256) {
        int c = i >> 4, d = i & 15;
        float s = 0.f;
#pragma unroll
        for (int r = 0; r < SL; ++r) s += g_sums[r * (B * KC * D) + b * (KC * D) + i];
        s_c[c * 17 + d] = s * s_ic[c];
    }
    __syncthreads();

    int adr[4][4];
#pragma unroll
    for (int i = 0; i < 4; ++i) {
        adr[i][0] = lab[i].x * 17;
        adr[i][1] = lab[i].y * 17;
        adr[i][2] = lab[i].z * 17;
        adr[i][3] = lab[i].w * 17;
    }

    float4 acc[4];
#pragma unroll
    for (int i = 0; i < 4; ++i) acc[i] = make_float4(0.f, 0.f, 0.f, 0.f);

#pragma unroll
    for (int d = 0; d < D; ++d) {
        if (d < D - 1) {
#pragma unroll
            for (int i = 0; i < 4; ++i)
                v[(d + 1) & 1][i] =
                    *(const float4*)(base + (size_t)(d + 1) * N + (i * 256 + t) * 4);
        }
#pragma unroll
        for (int i = 0; i < 4; ++i) {
            const float4 c = v[d & 1][i];
            float df;
            df = c.x - s_c[adr[i][0] + d]; acc[i].x += df * df;
            df = c.y - s_c[adr[i][1] + d]; acc[i].y += df * df;
            df = c.z - s_c[adr[i][2] + d]; acc[i].z += df * df;
            df = c.w - s_c[adr[i][3] + d]; acc[i].w += df * df;
        }
    }

    float hsum = 0.f;
#pragma unroll
    for (int i = 0; i < 4; ++i) {
        float h;
        h = fmaxf(sqrtf(acc[i].x) - DELTA_VAR, 0.f); hsum += h * h * s_ic[lab[i].x];
        h = fmaxf(sqrtf(acc[i].y) - DELTA_VAR, 0.f); hsum += h * h * s_ic[lab[i].y];
        h = fmaxf(sqrtf(acc[i].z) - DELTA_VAR, 0.f); hsum += h * h * s_ic[lab[i].z];
        h = fmaxf(sqrtf(acc[i].w) - DELTA_VAR, 0.f); hsum += h * h * s_ic[lab[i].w];
    }

    for (int o = 32; o > 0; o >>= 1) hsum += __shfl_down(hsum, o, 64);
    if ((t & 63) == 0) s_part[t >> 6] = hsum;
    __syncthreads();
    if (t == 0)
        atomicAdd(&g_varp[blockIdx.x & 63],
                  s_part[0] + s_part[1] + s_part[2] + s_part[3]);
}

// ---------------- Finalize: var + dist + reg -> scalar ----------------
__global__ __launch_bounds__(128) void k_final(const float* __restrict__ g_sums,
                                               const float* __restrict__ g_cnt,
                                               const float* __restrict__ g_varp,
                                               float* __restrict__ out) {
    __shared__ float s_c[B * KC * 17];
    __shared__ float s_red[2];
    const int t = threadIdx.x;

    float acc = 0.f;
    if (t < B * KC) {               // reg term + center build (sum the SL slices)
        float cnt = 0.f;
#pragma unroll
        for (int r = 0; r < SL; ++r) cnt += g_cnt[r * (B * KC) + t];
        float ns = 0.f;
        for (int d = 0; d < D; ++d) {
            float s = 0.f;
#pragma unroll
            for (int r = 0; r < SL; ++r) s += g_sums[r * (B * KC * D) + t * D + d];
            float c = s / cnt;
            s_c[t * 17 + d] = c;
            ns += c * c;
        }
        acc = sqrtf(ns) / (float)KC;
    }
    if (t < 64) acc += g_varp[t];   // var term partials
    __syncthreads();

    float dacc = 0.f;  // raw sum over [B,K,K] incl. diagonal (= delta_dist^2 each)
    for (int idx = t; idx < B * KC * KC; idx += 128) {
        int b = idx / (KC * KC);
        int r = idx % (KC * KC);
        int i = r / KC, j = r % KC;
        float hd;
        if (i == j) {
            hd = DELTA_DIST * DELTA_DIST;
        } else {
            const float* ci = &s_c[(b * KC + i) * 17];
            const float* cj = &s_c[(b * KC + j) * 17];
            float sq = 0.f;
            for (int d = 0; d < D; ++d) { float df = ci[d] - cj[d]; sq += df * df; }
            float hh = fmaxf(DELTA_DIST - sqrtf(sq), 0.f);
            hd = hh * hh;
        }
        dacc += hd;
    }
    float total = acc + dacc / (2.f * KC * (KC - 1));

    for (int o = 32; o > 0; o >>= 1) total += __shfl_down(total, o, 64);
    if ((t & 63) == 0) s_red[t >> 6] = total;
    __syncthreads();
    if (t == 0) out[0] = (s_red[0] + s_red[1]) / (float)B;
}

extern "C" void kernel_launch(void* const* d_in, const int* in_sizes, int n_in,
                              void* d_out, int out_size, void* d_ws, size_t ws_size,
                              hipStream_t stream) {
    const float* data  = (const float*)d_in[0];
    const int* labels  = (const int*)d_in[1];
    float* ws = (float*)d_ws;
    float* g_sums = ws;                                 // SL * 1536 = 12288
    float* g_cnt  = g_sums + SL * (B * KC * D);         // SL * 96   = 768
    float* g_varp = g_cnt  + SL * (B * KC);             // 64

    hipMemsetAsync(d_ws, 0,
                   (SL * (B * KC * D) + SL * (B * KC) + 64) * sizeof(float), stream);

    k_sums<<<BLOCKS, 256, 0, stream>>>(data, labels, g_sums, g_cnt);
    k_var <<<BLOCKS, 256, 0, stream>>>(data, labels, g_sums, g_cnt, g_varp);
    k_final<<<1, 128, 0, stream>>>(g_sums, g_cnt, g_varp, (float*)d_out);
}